// Round 6
// baseline (854.119 us; speedup 1.0000x reference)
//
#include <hip/hip_runtime.h>
#include <math.h>

#define NN 50000
#define NE 600000
#define HEADS 8
#define NB 4
#define NA 3
#define KC (NA*NB)   // 12 combine terms per head
#define OUT_T 349

// ---------------------------------------------------------------- degree count
__global__ void k_count(const int* __restrict__ row, int* __restrict__ deg) {
    int e = blockIdx.x * blockDim.x + threadIdx.x;
    if (e < NE) atomicAdd(&deg[row[e]], 1);
}

// ---------------------------------------------------------------- blocked exclusive scan (single block, 1024 thr)
__global__ __launch_bounds__(1024) void k_scan(const int* __restrict__ deg, int* __restrict__ rowptr) {
    __shared__ int partial[1024];
    const int tid = threadIdx.x;
    const int CH = 49;                 // 1024*49 = 50176 >= NN
    int base = tid * CH;
    int s = 0;
    for (int i = 0; i < CH; i++) { int idx = base + i; if (idx < NN) s += deg[idx]; }
    partial[tid] = s;
    __syncthreads();
    for (int off = 1; off < 1024; off <<= 1) {
        int t = (tid >= off) ? partial[tid - off] : 0;
        __syncthreads();
        partial[tid] += t;
        __syncthreads();
    }
    int excl = partial[tid] - s;
    for (int i = 0; i < CH; i++) {
        int idx = base + i;
        if (idx < NN) { rowptr[idx] = excl; excl += deg[idx]; }
    }
    if (tid == 1023) rowptr[NN] = partial[1023];
}

// ---------------------------------------------------------------- dinv
__global__ void k_dinv(const int* __restrict__ deg, float* __restrict__ dinv) {
    int n = blockIdx.x * blockDim.x + threadIdx.x;
    if (n < NN) {
        int d = deg[n];
        dinv[n] = (d > 0) ? rsqrtf((float)d) : 0.f;
    }
}

// ---------------------------------------------------------------- CSR fill
__global__ void k_fill(const int* __restrict__ row, const int* __restrict__ col,
                       const int* __restrict__ rowptr, int* __restrict__ cursor,
                       const float* __restrict__ dinv,
                       int* __restrict__ csr_col, float* __restrict__ csr_norm) {
    int e = blockIdx.x * blockDim.x + threadIdx.x;
    if (e < NE) {
        int r = row[e], c = col[e];
        int pos = rowptr[r] + atomicAdd(&cursor[r], 1);
        csr_col[pos] = c;
        csr_norm[pos] = dinv[r] * dinv[c];
    }
}

// ---------------------------------------------------------------- pack [Wb | Wc] -> Wcomb, [0 | bc] -> bcomb
__global__ void k_pack(const float* __restrict__ Wb, const float* __restrict__ Wc,
                       const float* __restrict__ bc, float* __restrict__ Wcomb,
                       float* __restrict__ bcomb, int K, int FB, int LD) {
    int idx = blockIdx.x * blockDim.x + threadIdx.x;
    int total = K * LD;
    if (idx < total) {
        int k = idx / LD, n = idx - k * LD;
        Wcomb[idx] = (n < FB) ? Wb[k * FB + n] : Wc[k * 96 + (n - FB)];
    }
    if (idx < LD) bcomb[idx] = (idx < FB) ? 0.f : bc[idx - FB];
}

// ---------------------------------------------------------------- f32 GEMM 64x128x32, 4x8 micro, swizzled LDS
// C[M x Nc] = A[M x K] @ W[K x Nc] + bias
// R5 post-mortem: 128x128/8x8 needed ~110 VGPR but allocator settles at 84 ->
// sa/sb spilled to scratch (WRITE 162MB vs 45MB ideal), and 782 blocks = 3/CU
// grid-starved occupancy (25%). 64x128/4x8 fits the 84-reg budget (acc 32 +
// prefetch 24 + addr ~22) and doubles the grid to 1564 blocks.
__global__ __launch_bounds__(256) void k_gemm(const float* __restrict__ A,
                                              const float* __restrict__ W,
                                              const float* __restrict__ bias,
                                              float* __restrict__ C,
                                              int M, int K, int Nc) {
    __shared__ float As[32 * 64];    // [k][m^swz(k)]  8 KB
    __shared__ float Bs[32 * 128];   // [k][slot-swizzled n]  16 KB
    const int tid = threadIdx.x;
    const int m0 = blockIdx.y * 64, n0 = blockIdx.x * 128;
    const int tr = tid >> 4, tc = tid & 15;
    const int arow = tid >> 3;                   // 0..31
    const int af4  = tid & 7;                    // k-group (4 k each)
    const int aswz = (af4 & 3) << 3;
    const int bkb = tid >> 4;
    const int bnf = tid & 15;
    const int bs0 = bnf ^ ((bnf >> 3) & 3);
    const int bs1 = (bnf + 16) ^ (((bnf + 16) >> 3) & 3);
    const int rs0 = (tc * 2) ^ (((tc * 2) >> 3) & 3);
    const int rs1 = (tc * 2 + 1) ^ (((tc * 2 + 1) >> 3) & 3);

    const float4 z4 = make_float4(0.f, 0.f, 0.f, 0.f);
    float4 sa[2], sb[4];
    const int nT = K >> 5;

    auto loadA = [&](int t) {
        int k0 = t * 32;
        #pragma unroll
        for (int p = 0; p < 2; p++) {
            int m = m0 + p * 32 + arow;
            sa[p] = (m < M) ? *(const float4*)&A[(size_t)m * K + k0 + af4 * 4] : z4;
        }
    };
    auto loadB = [&](int t) {
        int k0 = t * 32;
        int c0 = n0 + bnf * 4;
        int c1 = n0 + 64 + bnf * 4;
        #pragma unroll
        for (int h = 0; h < 2; h++) {
            int kk = k0 + bkb + h * 16;
            sb[h * 2 + 0] = (c0 < Nc) ? *(const float4*)&W[(size_t)kk * Nc + c0] : z4;
            sb[h * 2 + 1] = (c1 < Nc) ? *(const float4*)&W[(size_t)kk * Nc + c1] : z4;
        }
    };
    auto storeAB = [&]() {
        #pragma unroll
        for (int p = 0; p < 2; p++) {
            int ms = (p * 32 + arow) ^ aswz;
            As[(af4 * 4 + 0) * 64 + ms] = sa[p].x;
            As[(af4 * 4 + 1) * 64 + ms] = sa[p].y;
            As[(af4 * 4 + 2) * 64 + ms] = sa[p].z;
            As[(af4 * 4 + 3) * 64 + ms] = sa[p].w;
        }
        *(float4*)&Bs[bkb * 128 + bs0 * 4] = sb[0];
        *(float4*)&Bs[bkb * 128 + bs1 * 4] = sb[1];
        *(float4*)&Bs[(bkb + 16) * 128 + bs0 * 4] = sb[2];
        *(float4*)&Bs[(bkb + 16) * 128 + bs1 * 4] = sb[3];
    };

    float acc[4][8] = {};
    loadA(0); loadB(0);
    for (int t = 0; t < nT; t++) {
        __syncthreads();
        storeAB();
        __syncthreads();
        if (t + 1 < nT) { loadA(t + 1); loadB(t + 1); }
        #pragma unroll 8
        for (int k = 0; k < 32; k++) {
            int kswz = ((k >> 2) & 3) << 3;
            const float4 a0 = *(const float4*)&As[k * 64 + ((tr * 4) ^ kswz)];
            const float4 b0 = *(const float4*)&Bs[k * 128 + rs0 * 4];
            const float4 b1 = *(const float4*)&Bs[k * 128 + rs1 * 4];
            const float a[4] = {a0.x, a0.y, a0.z, a0.w};
            const float b[8] = {b0.x, b0.y, b0.z, b0.w, b1.x, b1.y, b1.z, b1.w};
            #pragma unroll
            for (int i = 0; i < 4; i++)
                #pragma unroll
                for (int j = 0; j < 8; j++)
                    acc[i][j] = fmaf(a[i], b[j], acc[i][j]);
        }
    }

    const int nc0 = n0 + tc * 8;
    if (nc0 < Nc) {   // Nc % 8 == 0, whole 8-col group is in or out
        const float4 bi0 = *(const float4*)&bias[nc0];
        const float4 bi1 = *(const float4*)&bias[nc0 + 4];
        #pragma unroll
        for (int i = 0; i < 4; i++) {
            int m = m0 + tr * 4 + i;
            if (m >= M) continue;
            float4 o0, o1;
            o0.x = acc[i][0] + bi0.x; o0.y = acc[i][1] + bi0.y;
            o0.z = acc[i][2] + bi0.z; o0.w = acc[i][3] + bi0.w;
            o1.x = acc[i][4] + bi1.x; o1.y = acc[i][5] + bi1.y;
            o1.z = acc[i][6] + bi1.z; o1.w = acc[i][7] + bi1.w;
            *(float4*)&C[(size_t)m * Nc + nc0] = o0;
            *(float4*)&C[(size_t)m * Nc + nc0 + 4] = o1;
        }
    }
}

// ---------------------------------------------------------------- fused gather + 3 aggregators + combine (+relu / +log_softmax)
// one WAVE per node; lane owns a float2 feature pair; 4-edge manual unroll for MLP
template<int FB, int F, int DOUT, int FINAL, int LD>
__global__ __launch_bounds__(256) void k_agg(const float* __restrict__ fused,
                                             const float* __restrict__ bias,
                                             const int* __restrict__ rowptr,
                                             const int* __restrict__ csr_col,
                                             const float* __restrict__ csr_norm,
                                             float* __restrict__ out) {
    constexpr int NS  = (FB + 127) / 128;  // float2 slots per lane
    constexpr int OPL = (DOUT + 63) / 64;  // outputs per lane
    const int wid  = threadIdx.x >> 6;
    const int lane = threadIdx.x & 63;
    const int n = blockIdx.x * 4 + wid;    // grid is exactly NN/4 blocks

    __shared__ int   s_col[4][64];
    __shared__ float s_nrm[4][64];
    __shared__ float s_w[4][HEADS * KC];
    __shared__ float s_agg[4][KC * F];

    // stage combine weights (96 floats) for this node
    const float* wsrc = fused + (size_t)n * LD + FB;
    s_w[wid][lane] = wsrc[lane];
    if (lane < HEADS * KC - 64) s_w[wid][64 + lane] = wsrc[64 + lane];

    const int start = rowptr[n], end = rowptr[n + 1];
    float2 sum[NS], ssum[NS], mx[NS];
    #pragma unroll
    for (int s = 0; s < NS; s++) {
        sum[s] = make_float2(0.f, 0.f);
        ssum[s] = make_float2(0.f, 0.f);
        mx[s] = make_float2(-3.402823466e38f, -3.402823466e38f);
    }

    for (int e0 = start; e0 < end; e0 += 64) {
        int cnt = min(64, end - e0);
        if (lane < cnt) {
            s_col[wid][lane] = csr_col[e0 + lane];
            s_nrm[wid][lane] = csr_norm[e0 + lane];
        }
        __builtin_amdgcn_wave_barrier();   // wave-synchronous: in-order LDS pipe makes RAW safe
        int j = 0;
        for (; j + 4 <= cnt; j += 4) {
            const int4   cc = *(const int4*)&s_col[wid][j];
            const float4 nn = *(const float4*)&s_nrm[wid][j];
            #pragma unroll
            for (int s = 0; s < NS; s++) {
                const int feat = s * 128 + lane * 2;
                if (feat < FB) {
                    const float2 v0 = *(const float2*)&fused[(size_t)cc.x * LD + feat];
                    const float2 v1 = *(const float2*)&fused[(size_t)cc.y * LD + feat];
                    const float2 v2 = *(const float2*)&fused[(size_t)cc.z * LD + feat];
                    const float2 v3 = *(const float2*)&fused[(size_t)cc.w * LD + feat];
                    sum[s].x += (v0.x + v1.x) + (v2.x + v3.x);
                    sum[s].y += (v0.y + v1.y) + (v2.y + v3.y);
                    ssum[s].x = fmaf(v0.x, nn.x, fmaf(v1.x, nn.y, fmaf(v2.x, nn.z, fmaf(v3.x, nn.w, ssum[s].x))));
                    ssum[s].y = fmaf(v0.y, nn.x, fmaf(v1.y, nn.y, fmaf(v2.y, nn.z, fmaf(v3.y, nn.w, ssum[s].y))));
                    mx[s].x = fmaxf(mx[s].x, fmaxf(fmaxf(v0.x, v1.x), fmaxf(v2.x, v3.x)));
                    mx[s].y = fmaxf(mx[s].y, fmaxf(fmaxf(v0.y, v1.y), fmaxf(v2.y, v3.y)));
                }
            }
        }
        for (; j < cnt; j++) {
            const int   c  = s_col[wid][j];
            const float nr = s_nrm[wid][j];
            #pragma unroll
            for (int s = 0; s < NS; s++) {
                const int feat = s * 128 + lane * 2;
                if (feat < FB) {
                    const float2 v = *(const float2*)&fused[(size_t)c * LD + feat];
                    sum[s].x += v.x;             sum[s].y += v.y;
                    ssum[s].x = fmaf(v.x, nr, ssum[s].x);
                    ssum[s].y = fmaf(v.y, nr, ssum[s].y);
                    mx[s].x = fmaxf(mx[s].x, v.x);
                    mx[s].y = fmaxf(mx[s].y, v.y);
                }
            }
        }
        __builtin_amdgcn_wave_barrier();
    }

    const float degf = (float)(end - start);
    const float rdeg = 1.f / fmaxf(degf, 1.f);
    const bool nonempty = degf > 0.f;
    #pragma unroll
    for (int s = 0; s < NS; s++) {
        const int feat = s * 128 + lane * 2;
        if (feat < FB) {
            const int nb = feat / F, f = feat - nb * F;
            float2 mean = make_float2(sum[s].x * rdeg, sum[s].y * rdeg);
            float2 mxv  = nonempty ? mx[s] : make_float2(0.f, 0.f);
            *(float2*)&s_agg[wid][(0 * NB + nb) * F + f] = ssum[s];
            *(float2*)&s_agg[wid][(1 * NB + nb) * F + f] = mean;
            *(float2*)&s_agg[wid][(2 * NB + nb) * F + f] = mxv;
        }
    }
    __builtin_amdgcn_wave_barrier();

    float ov[OPL];
    #pragma unroll
    for (int q = 0; q < OPL; q++) {
        int o = lane + q * 64;
        if (o < DOUT) {
            int h = o / F, f = o - h * F;
            float v = bias[o];
            #pragma unroll
            for (int k = 0; k < KC; k++) v = fmaf(s_w[wid][h * KC + k], s_agg[wid][k * F + f], v);
            ov[q] = v;
        } else {
            ov[q] = -3.402823466e38f;
        }
    }

    if constexpr (FINAL == 0) {
        #pragma unroll
        for (int q = 0; q < OPL; q++) {
            int o = lane + q * 64;
            if (o < DOUT) out[(size_t)n * DOUT + o] = fmaxf(ov[q], 0.f);
        }
    } else {
        float m = -3.402823466e38f;
        #pragma unroll
        for (int q = 0; q < OPL; q++) { int o = lane + q * 64; if (o < OUT_T) m = fmaxf(m, ov[q]); }
        #pragma unroll
        for (int off = 32; off >= 1; off >>= 1) m = fmaxf(m, __shfl_xor(m, off, 64));
        float s = 0.f;
        #pragma unroll
        for (int q = 0; q < OPL; q++) { int o = lane + q * 64; if (o < OUT_T) s += expf(ov[q] - m); }
        #pragma unroll
        for (int off = 32; off >= 1; off >>= 1) s += __shfl_xor(s, off, 64);
        float lse = m + logf(s);
        #pragma unroll
        for (int q = 0; q < OPL; q++) {
            int o = lane + q * 64;
            if (o < OUT_T) out[(size_t)n * OUT_T + o] = ov[q] - lse;
        }
    }
}

// ---------------------------------------------------------------- launch
extern "C" void kernel_launch(void* const* d_in, const int* in_sizes, int n_in,
                              void* d_out, int out_size, void* d_ws, size_t ws_size,
                              hipStream_t stream) {
    const float* x   = (const float*)d_in[0];
    const int*   ei  = (const int*)d_in[1];
    const int*   row = ei;
    const int*   col = ei + NE;
    const float* Wb0 = (const float*)d_in[2];
    const float* Wc0 = (const float*)d_in[3];
    const float* bc0 = (const float*)d_in[4];
    const float* b0  = (const float*)d_in[5];
    const float* Wb1 = (const float*)d_in[6];
    const float* Wc1 = (const float*)d_in[7];
    const float* bc1 = (const float*)d_in[8];
    const float* b1  = (const float*)d_in[9];
    const float* Wb2 = (const float*)d_in[10];
    const float* Wc2 = (const float*)d_in[11];
    const float* bc2 = (const float*)d_in[12];
    const float* b2  = (const float*)d_in[13];
    float* out = (float*)d_out;

    // workspace carve (256B aligned slots)
    char* w = (char*)d_ws;
    size_t off = 0;
    auto carve = [&](size_t elems) { void* p = w + off; off += ((elems * 4 + 255) / 256) * 256; return p; };
    int*   deg      = (int*)  carve(NN);
    int*   cursor   = (int*)  carve(NN);
    int*   rowptr   = (int*)  carve(NN + 1);
    float* dinv     = (float*)carve(NN);
    int*   csr_col  = (int*)  carve(NE);
    float* csr_norm = (float*)carve(NE);
    float* fused    = (float*)carve((size_t)NN * 272);   // bases|comb, reused all 3 layers
    float* h2       = (float*)carve((size_t)NN * 256);
    float* Wcomb    = (float*)carve(256 * 272);
    float* bcomb    = (float*)carve(272);
    float* h1       = out;   // layer-0 hidden in d_out slack (51.2MB < 69.8MB)

    hipMemsetAsync(deg, 0, NN * sizeof(int), stream);
    hipMemsetAsync(cursor, 0, NN * sizeof(int), stream);

    k_count<<<(NE + 255) / 256, 256, 0, stream>>>(row, deg);
    k_scan<<<1, 1024, 0, stream>>>(deg, rowptr);
    k_dinv<<<(NN + 255) / 256, 256, 0, stream>>>(deg, dinv);
    k_fill<<<(NE + 255) / 256, 256, 0, stream>>>(row, col, rowptr, cursor, dinv, csr_col, csr_norm);

    const int my = (NN + 63) / 64;   // 782 row-panels of 64

    // ---- layer 0: K=128, Nc=224 (FB=128 | 96)
    k_pack<<<(128 * 224 + 255) / 256, 256, 0, stream>>>(Wb0, Wc0, bc0, Wcomb, bcomb, 128, 128, 224);
    k_gemm<<<dim3(2, my), 256, 0, stream>>>(x, Wcomb, bcomb, fused, NN, 128, 224);
    k_agg<128, 32, 256, 0, 224><<<NN / 4, 256, 0, stream>>>(fused, b0, rowptr, csr_col, csr_norm, h1);

    // ---- layer 1: K=256, Nc=224
    k_pack<<<(256 * 224 + 255) / 256, 256, 0, stream>>>(Wb1, Wc1, bc1, Wcomb, bcomb, 256, 128, 224);
    k_gemm<<<dim3(2, my), 256, 0, stream>>>(h1, Wcomb, bcomb, fused, NN, 256, 224);
    k_agg<128, 32, 256, 0, 224><<<NN / 4, 256, 0, stream>>>(fused, b1, rowptr, csr_col, csr_norm, h2);

    // ---- layer 2: K=256, Nc=272 (FB=176 | 96), fused log_softmax -> d_out
    k_pack<<<(256 * 272 + 255) / 256, 256, 0, stream>>>(Wb2, Wc2, bc2, Wcomb, bcomb, 256, 176, 272);
    k_gemm<<<dim3(3, my), 256, 0, stream>>>(h2, Wcomb, bcomb, fused, NN, 256, 272);
    k_agg<176, 44, 352, 1, 272><<<NN / 4, 256, 0, stream>>>(fused, b2, rowptr, csr_col, csr_norm, out);
}

// Round 7
// 845.556 us; speedup vs baseline: 1.0101x; 1.0101x over previous
//
#include <hip/hip_runtime.h>
#include <math.h>

#define NN 50000
#define NE 600000
#define HEADS 8
#define NB 4
#define NA 3
#define KC (NA*NB)   // 12 combine terms per head
#define OUT_T 349

// ---------------------------------------------------------------- degree count
__global__ void k_count(const int* __restrict__ row, int* __restrict__ deg) {
    int e = blockIdx.x * blockDim.x + threadIdx.x;
    if (e < NE) atomicAdd(&deg[row[e]], 1);
}

// ---------------------------------------------------------------- blocked exclusive scan (single block, 1024 thr)
__global__ __launch_bounds__(1024) void k_scan(const int* __restrict__ deg, int* __restrict__ rowptr) {
    __shared__ int partial[1024];
    const int tid = threadIdx.x;
    const int CH = 49;                 // 1024*49 = 50176 >= NN
    int base = tid * CH;
    int s = 0;
    for (int i = 0; i < CH; i++) { int idx = base + i; if (idx < NN) s += deg[idx]; }
    partial[tid] = s;
    __syncthreads();
    for (int off = 1; off < 1024; off <<= 1) {
        int t = (tid >= off) ? partial[tid - off] : 0;
        __syncthreads();
        partial[tid] += t;
        __syncthreads();
    }
    int excl = partial[tid] - s;
    for (int i = 0; i < CH; i++) {
        int idx = base + i;
        if (idx < NN) { rowptr[idx] = excl; excl += deg[idx]; }
    }
    if (tid == 1023) rowptr[NN] = partial[1023];
}

// ---------------------------------------------------------------- dinv
__global__ void k_dinv(const int* __restrict__ deg, float* __restrict__ dinv) {
    int n = blockIdx.x * blockDim.x + threadIdx.x;
    if (n < NN) {
        int d = deg[n];
        dinv[n] = (d > 0) ? rsqrtf((float)d) : 0.f;
    }
}

// ---------------------------------------------------------------- CSR fill
__global__ void k_fill(const int* __restrict__ row, const int* __restrict__ col,
                       const int* __restrict__ rowptr, int* __restrict__ cursor,
                       const float* __restrict__ dinv,
                       int* __restrict__ csr_col, float* __restrict__ csr_norm) {
    int e = blockIdx.x * blockDim.x + threadIdx.x;
    if (e < NE) {
        int r = row[e], c = col[e];
        int pos = rowptr[r] + atomicAdd(&cursor[r], 1);
        csr_col[pos] = c;
        csr_norm[pos] = dinv[r] * dinv[c];
    }
}

// ---------------------------------------------------------------- pack [Wb | Wc] -> Wcomb, [0 | bc] -> bcomb
__global__ void k_pack(const float* __restrict__ Wb, const float* __restrict__ Wc,
                       const float* __restrict__ bc, float* __restrict__ Wcomb,
                       float* __restrict__ bcomb, int K, int FB, int LD) {
    int idx = blockIdx.x * blockDim.x + threadIdx.x;
    int total = K * LD;
    if (idx < total) {
        int k = idx / LD, n = idx - k * LD;
        Wcomb[idx] = (n < FB) ? Wb[k * FB + n] : Wc[k * 96 + (n - FB)];
    }
    if (idx < LD) bcomb[idx] = (idx < FB) ? 0.f : bc[idx - FB];
}

// ---------------------------------------------------------------- f32 GEMM 128x128x32, 8x8 micro, swizzled LDS
// C[M x Nc] = A[M x K] @ W[K x Nc] + bias
// R6 post-mortem: allocator picked 40/84/40 VGPRs across three geometries and
// spilled the accumulator — LLVM's perf-hint "memory-bound" heuristic targets
// high occupancy and caps regs regardless of demand. launch_bounds(,2) only
// sets a MIN waves/EU (reg ceiling), never lowers the occupancy TARGET.
// amdgpu_waves_per_eu(2,2) pins the target: budget = 512/2 = 256 VGPRs.
__global__ __launch_bounds__(256) __attribute__((amdgpu_waves_per_eu(2, 2)))
void k_gemm(const float* __restrict__ A,
            const float* __restrict__ W,
            const float* __restrict__ bias,
            float* __restrict__ C,
            int M, int K, int Nc) {
    __shared__ float As[32 * 128];   // [k][m^swz(k)]
    __shared__ float Bs[32 * 128];   // [k][slot-swizzled n]
    const int tid = threadIdx.x;
    const int m0 = blockIdx.y * 128, n0 = blockIdx.x * 128;
    const int tr = tid >> 4, tc = tid & 15;
    const int arow = tid >> 3;
    const int af4  = tid & 7;
    const int aswz = (af4 & 3) << 3;
    const int bkb = tid >> 4;
    const int bnf = tid & 15;
    const int bs0 = bnf ^ ((bnf >> 3) & 3);
    const int bs1 = (bnf + 16) ^ (((bnf + 16) >> 3) & 3);
    const int rs0 = (tc * 2) ^ (((tc * 2) >> 3) & 3);
    const int rs1 = (tc * 2 + 1) ^ (((tc * 2 + 1) >> 3) & 3);

    const float4 z4 = make_float4(0.f, 0.f, 0.f, 0.f);
    float4 sa[4], sb[4];
    const int nT = K >> 5;

    auto loadA = [&](int t) {
        int k0 = t * 32;
        #pragma unroll
        for (int p = 0; p < 4; p++) {
            int m = m0 + p * 32 + arow;
            sa[p] = (m < M) ? *(const float4*)&A[(size_t)m * K + k0 + af4 * 4] : z4;
        }
    };
    auto loadB = [&](int t) {
        int k0 = t * 32;
        int c0 = n0 + bnf * 4;
        int c1 = n0 + 64 + bnf * 4;
        #pragma unroll
        for (int h = 0; h < 2; h++) {
            int kk = k0 + bkb + h * 16;
            sb[h * 2 + 0] = (c0 < Nc) ? *(const float4*)&W[(size_t)kk * Nc + c0] : z4;
            sb[h * 2 + 1] = (c1 < Nc) ? *(const float4*)&W[(size_t)kk * Nc + c1] : z4;
        }
    };
    auto storeAB = [&]() {
        #pragma unroll
        for (int p = 0; p < 4; p++) {
            int ms = (p * 32 + arow) ^ aswz;
            As[(af4 * 4 + 0) * 128 + ms] = sa[p].x;
            As[(af4 * 4 + 1) * 128 + ms] = sa[p].y;
            As[(af4 * 4 + 2) * 128 + ms] = sa[p].z;
            As[(af4 * 4 + 3) * 128 + ms] = sa[p].w;
        }
        *(float4*)&Bs[bkb * 128 + bs0 * 4] = sb[0];
        *(float4*)&Bs[bkb * 128 + bs1 * 4] = sb[1];
        *(float4*)&Bs[(bkb + 16) * 128 + bs0 * 4] = sb[2];
        *(float4*)&Bs[(bkb + 16) * 128 + bs1 * 4] = sb[3];
    };

    float acc[8][8] = {};
    loadA(0); loadB(0);
    for (int t = 0; t < nT; t++) {
        __syncthreads();
        storeAB();
        __syncthreads();
        if (t + 1 < nT) { loadA(t + 1); loadB(t + 1); }
        #pragma unroll 8
        for (int k = 0; k < 32; k++) {
            int kswz = ((k >> 2) & 3) << 3;
            int abase = k * 128 + ((tr * 8) ^ kswz);
            const float4 a0 = *(const float4*)&As[abase];
            const float4 a1 = *(const float4*)&As[abase + 4];
            const float4 b0 = *(const float4*)&Bs[k * 128 + rs0 * 4];
            const float4 b1 = *(const float4*)&Bs[k * 128 + rs1 * 4];
            const float a[8] = {a0.x, a0.y, a0.z, a0.w, a1.x, a1.y, a1.z, a1.w};
            const float b[8] = {b0.x, b0.y, b0.z, b0.w, b1.x, b1.y, b1.z, b1.w};
            #pragma unroll
            for (int i = 0; i < 8; i++)
                #pragma unroll
                for (int j = 0; j < 8; j++)
                    acc[i][j] = fmaf(a[i], b[j], acc[i][j]);
        }
    }

    const int nc0 = n0 + tc * 8;
    if (nc0 < Nc) {   // Nc % 8 == 0, whole 8-col group is in or out
        const float4 bi0 = *(const float4*)&bias[nc0];
        const float4 bi1 = *(const float4*)&bias[nc0 + 4];
        #pragma unroll
        for (int i = 0; i < 8; i++) {
            int m = m0 + tr * 8 + i;
            if (m >= M) continue;
            float4 o0, o1;
            o0.x = acc[i][0] + bi0.x; o0.y = acc[i][1] + bi0.y;
            o0.z = acc[i][2] + bi0.z; o0.w = acc[i][3] + bi0.w;
            o1.x = acc[i][4] + bi1.x; o1.y = acc[i][5] + bi1.y;
            o1.z = acc[i][6] + bi1.z; o1.w = acc[i][7] + bi1.w;
            *(float4*)&C[(size_t)m * Nc + nc0] = o0;
            *(float4*)&C[(size_t)m * Nc + nc0 + 4] = o1;
        }
    }
}

// ---------------------------------------------------------------- fused gather + 3 aggregators + combine (+relu / +log_softmax)
// one WAVE per node; lane owns a float2 feature pair; 4-edge manual unroll for MLP
template<int FB, int F, int DOUT, int FINAL, int LD>
__global__ __launch_bounds__(256) void k_agg(const float* __restrict__ fused,
                                             const float* __restrict__ bias,
                                             const int* __restrict__ rowptr,
                                             const int* __restrict__ csr_col,
                                             const float* __restrict__ csr_norm,
                                             float* __restrict__ out) {
    constexpr int NS  = (FB + 127) / 128;  // float2 slots per lane
    constexpr int OPL = (DOUT + 63) / 64;  // outputs per lane
    const int wid  = threadIdx.x >> 6;
    const int lane = threadIdx.x & 63;
    const int n = blockIdx.x * 4 + wid;    // grid is exactly NN/4 blocks

    __shared__ int   s_col[4][64];
    __shared__ float s_nrm[4][64];
    __shared__ float s_w[4][HEADS * KC];
    __shared__ float s_agg[4][KC * F];

    // stage combine weights (96 floats) for this node
    const float* wsrc = fused + (size_t)n * LD + FB;
    s_w[wid][lane] = wsrc[lane];
    if (lane < HEADS * KC - 64) s_w[wid][64 + lane] = wsrc[64 + lane];

    const int start = rowptr[n], end = rowptr[n + 1];
    float2 sum[NS], ssum[NS], mx[NS];
    #pragma unroll
    for (int s = 0; s < NS; s++) {
        sum[s] = make_float2(0.f, 0.f);
        ssum[s] = make_float2(0.f, 0.f);
        mx[s] = make_float2(-3.402823466e38f, -3.402823466e38f);
    }

    for (int e0 = start; e0 < end; e0 += 64) {
        int cnt = min(64, end - e0);
        if (lane < cnt) {
            s_col[wid][lane] = csr_col[e0 + lane];
            s_nrm[wid][lane] = csr_norm[e0 + lane];
        }
        __builtin_amdgcn_wave_barrier();   // wave-synchronous: in-order LDS pipe makes RAW safe
        int j = 0;
        for (; j + 4 <= cnt; j += 4) {
            const int4   cc = *(const int4*)&s_col[wid][j];
            const float4 nn = *(const float4*)&s_nrm[wid][j];
            #pragma unroll
            for (int s = 0; s < NS; s++) {
                const int feat = s * 128 + lane * 2;
                if (feat < FB) {
                    const float2 v0 = *(const float2*)&fused[(size_t)cc.x * LD + feat];
                    const float2 v1 = *(const float2*)&fused[(size_t)cc.y * LD + feat];
                    const float2 v2 = *(const float2*)&fused[(size_t)cc.z * LD + feat];
                    const float2 v3 = *(const float2*)&fused[(size_t)cc.w * LD + feat];
                    sum[s].x += (v0.x + v1.x) + (v2.x + v3.x);
                    sum[s].y += (v0.y + v1.y) + (v2.y + v3.y);
                    ssum[s].x = fmaf(v0.x, nn.x, fmaf(v1.x, nn.y, fmaf(v2.x, nn.z, fmaf(v3.x, nn.w, ssum[s].x))));
                    ssum[s].y = fmaf(v0.y, nn.x, fmaf(v1.y, nn.y, fmaf(v2.y, nn.z, fmaf(v3.y, nn.w, ssum[s].y))));
                    mx[s].x = fmaxf(mx[s].x, fmaxf(fmaxf(v0.x, v1.x), fmaxf(v2.x, v3.x)));
                    mx[s].y = fmaxf(mx[s].y, fmaxf(fmaxf(v0.y, v1.y), fmaxf(v2.y, v3.y)));
                }
            }
        }
        for (; j < cnt; j++) {
            const int   c  = s_col[wid][j];
            const float nr = s_nrm[wid][j];
            #pragma unroll
            for (int s = 0; s < NS; s++) {
                const int feat = s * 128 + lane * 2;
                if (feat < FB) {
                    const float2 v = *(const float2*)&fused[(size_t)c * LD + feat];
                    sum[s].x += v.x;             sum[s].y += v.y;
                    ssum[s].x = fmaf(v.x, nr, ssum[s].x);
                    ssum[s].y = fmaf(v.y, nr, ssum[s].y);
                    mx[s].x = fmaxf(mx[s].x, v.x);
                    mx[s].y = fmaxf(mx[s].y, v.y);
                }
            }
        }
        __builtin_amdgcn_wave_barrier();
    }

    const float degf = (float)(end - start);
    const float rdeg = 1.f / fmaxf(degf, 1.f);
    const bool nonempty = degf > 0.f;
    #pragma unroll
    for (int s = 0; s < NS; s++) {
        const int feat = s * 128 + lane * 2;
        if (feat < FB) {
            const int nb = feat / F, f = feat - nb * F;
            float2 mean = make_float2(sum[s].x * rdeg, sum[s].y * rdeg);
            float2 mxv  = nonempty ? mx[s] : make_float2(0.f, 0.f);
            *(float2*)&s_agg[wid][(0 * NB + nb) * F + f] = ssum[s];
            *(float2*)&s_agg[wid][(1 * NB + nb) * F + f] = mean;
            *(float2*)&s_agg[wid][(2 * NB + nb) * F + f] = mxv;
        }
    }
    __builtin_amdgcn_wave_barrier();

    float ov[OPL];
    #pragma unroll
    for (int q = 0; q < OPL; q++) {
        int o = lane + q * 64;
        if (o < DOUT) {
            int h = o / F, f = o - h * F;
            float v = bias[o];
            #pragma unroll
            for (int k = 0; k < KC; k++) v = fmaf(s_w[wid][h * KC + k], s_agg[wid][k * F + f], v);
            ov[q] = v;
        } else {
            ov[q] = -3.402823466e38f;
        }
    }

    if constexpr (FINAL == 0) {
        #pragma unroll
        for (int q = 0; q < OPL; q++) {
            int o = lane + q * 64;
            if (o < DOUT) out[(size_t)n * DOUT + o] = fmaxf(ov[q], 0.f);
        }
    } else {
        float m = -3.402823466e38f;
        #pragma unroll
        for (int q = 0; q < OPL; q++) { int o = lane + q * 64; if (o < OUT_T) m = fmaxf(m, ov[q]); }
        #pragma unroll
        for (int off = 32; off >= 1; off >>= 1) m = fmaxf(m, __shfl_xor(m, off, 64));
        float s = 0.f;
        #pragma unroll
        for (int q = 0; q < OPL; q++) { int o = lane + q * 64; if (o < OUT_T) s += expf(ov[q] - m); }
        #pragma unroll
        for (int off = 32; off >= 1; off >>= 1) s += __shfl_xor(s, off, 64);
        float lse = m + logf(s);
        #pragma unroll
        for (int q = 0; q < OPL; q++) {
            int o = lane + q * 64;
            if (o < OUT_T) out[(size_t)n * OUT_T + o] = ov[q] - lse;
        }
    }
}

// ---------------------------------------------------------------- launch
extern "C" void kernel_launch(void* const* d_in, const int* in_sizes, int n_in,
                              void* d_out, int out_size, void* d_ws, size_t ws_size,
                              hipStream_t stream) {
    const float* x   = (const float*)d_in[0];
    const int*   ei  = (const int*)d_in[1];
    const int*   row = ei;
    const int*   col = ei + NE;
    const float* Wb0 = (const float*)d_in[2];
    const float* Wc0 = (const float*)d_in[3];
    const float* bc0 = (const float*)d_in[4];
    const float* b0  = (const float*)d_in[5];
    const float* Wb1 = (const float*)d_in[6];
    const float* Wc1 = (const float*)d_in[7];
    const float* bc1 = (const float*)d_in[8];
    const float* b1  = (const float*)d_in[9];
    const float* Wb2 = (const float*)d_in[10];
    const float* Wc2 = (const float*)d_in[11];
    const float* bc2 = (const float*)d_in[12];
    const float* b2  = (const float*)d_in[13];
    float* out = (float*)d_out;

    // workspace carve (256B aligned slots)
    char* w = (char*)d_ws;
    size_t off = 0;
    auto carve = [&](size_t elems) { void* p = w + off; off += ((elems * 4 + 255) / 256) * 256; return p; };
    int*   deg      = (int*)  carve(NN);
    int*   cursor   = (int*)  carve(NN);
    int*   rowptr   = (int*)  carve(NN + 1);
    float* dinv     = (float*)carve(NN);
    int*   csr_col  = (int*)  carve(NE);
    float* csr_norm = (float*)carve(NE);
    float* fused    = (float*)carve((size_t)NN * 272);   // bases|comb, reused all 3 layers
    float* h2       = (float*)carve((size_t)NN * 256);
    float* Wcomb    = (float*)carve(256 * 272);
    float* bcomb    = (float*)carve(272);
    float* h1       = out;   // layer-0 hidden in d_out slack (51.2MB < 69.8MB)

    hipMemsetAsync(deg, 0, NN * sizeof(int), stream);
    hipMemsetAsync(cursor, 0, NN * sizeof(int), stream);

    k_count<<<(NE + 255) / 256, 256, 0, stream>>>(row, deg);
    k_scan<<<1, 1024, 0, stream>>>(deg, rowptr);
    k_dinv<<<(NN + 255) / 256, 256, 0, stream>>>(deg, dinv);
    k_fill<<<(NE + 255) / 256, 256, 0, stream>>>(row, col, rowptr, cursor, dinv, csr_col, csr_norm);

    const int my = (NN + 127) / 128;   // 391 row-panels of 128

    // ---- layer 0: K=128, Nc=224 (FB=128 | 96)
    k_pack<<<(128 * 224 + 255) / 256, 256, 0, stream>>>(Wb0, Wc0, bc0, Wcomb, bcomb, 128, 128, 224);
    k_gemm<<<dim3(2, my), 256, 0, stream>>>(x, Wcomb, bcomb, fused, NN, 128, 224);
    k_agg<128, 32, 256, 0, 224><<<NN / 4, 256, 0, stream>>>(fused, b0, rowptr, csr_col, csr_norm, h1);

    // ---- layer 1: K=256, Nc=224
    k_pack<<<(256 * 224 + 255) / 256, 256, 0, stream>>>(Wb1, Wc1, bc1, Wcomb, bcomb, 256, 128, 224);
    k_gemm<<<dim3(2, my), 256, 0, stream>>>(h1, Wcomb, bcomb, fused, NN, 256, 224);
    k_agg<128, 32, 256, 0, 224><<<NN / 4, 256, 0, stream>>>(fused, b1, rowptr, csr_col, csr_norm, h2);

    // ---- layer 2: K=256, Nc=272 (FB=176 | 96), fused log_softmax -> d_out
    k_pack<<<(256 * 272 + 255) / 256, 256, 0, stream>>>(Wb2, Wc2, bc2, Wcomb, bcomb, 256, 176, 272);
    k_gemm<<<dim3(3, my), 256, 0, stream>>>(h2, Wcomb, bcomb, fused, NN, 256, 272);
    k_agg<176, 44, 352, 1, 272><<<NN / 4, 256, 0, stream>>>(fused, b2, rowptr, csr_col, csr_norm, out);
}

// Round 9
// 621.734 us; speedup vs baseline: 1.3738x; 1.3600x over previous
//
#include <hip/hip_runtime.h>
#include <math.h>

#define NN 50000
#define NE 600000
#define HEADS 8
#define NB 4
#define NA 3
#define KC (NA*NB)   // 12 combine terms per head
#define OUT_T 349

typedef _Float16 half8 __attribute__((ext_vector_type(8)));
typedef float f32x4 __attribute__((ext_vector_type(4)));

// ---------------------------------------------------------------- degree count
__global__ void k_count(const int* __restrict__ row, int* __restrict__ deg) {
    int e = blockIdx.x * blockDim.x + threadIdx.x;
    if (e < NE) atomicAdd(&deg[row[e]], 1);
}

// ---------------------------------------------------------------- blocked exclusive scan (single block, 1024 thr)
__global__ __launch_bounds__(1024) void k_scan(const int* __restrict__ deg, int* __restrict__ rowptr) {
    __shared__ int partial[1024];
    const int tid = threadIdx.x;
    const int CH = 49;                 // 1024*49 = 50176 >= NN
    int base = tid * CH;
    int s = 0;
    for (int i = 0; i < CH; i++) { int idx = base + i; if (idx < NN) s += deg[idx]; }
    partial[tid] = s;
    __syncthreads();
    for (int off = 1; off < 1024; off <<= 1) {
        int t = (tid >= off) ? partial[tid - off] : 0;
        __syncthreads();
        partial[tid] += t;
        __syncthreads();
    }
    int excl = partial[tid] - s;
    for (int i = 0; i < CH; i++) {
        int idx = base + i;
        if (idx < NN) { rowptr[idx] = excl; excl += deg[idx]; }
    }
    if (tid == 1023) rowptr[NN] = partial[1023];
}

// ---------------------------------------------------------------- dinv
__global__ void k_dinv(const int* __restrict__ deg, float* __restrict__ dinv) {
    int n = blockIdx.x * blockDim.x + threadIdx.x;
    if (n < NN) {
        int d = deg[n];
        dinv[n] = (d > 0) ? rsqrtf((float)d) : 0.f;
    }
}

// ---------------------------------------------------------------- CSR fill
__global__ void k_fill(const int* __restrict__ row, const int* __restrict__ col,
                       const int* __restrict__ rowptr, int* __restrict__ cursor,
                       const float* __restrict__ dinv,
                       int* __restrict__ csr_col, float* __restrict__ csr_norm) {
    int e = blockIdx.x * blockDim.x + threadIdx.x;
    if (e < NE) {
        int r = row[e], c = col[e];
        int pos = rowptr[r] + atomicAdd(&cursor[r], 1);
        csr_col[pos] = c;
        csr_norm[pos] = dinv[r] * dinv[c];
    }
}

// ---------------------------------------------------------------- pack & split: W[K][*] -> WhT/WlT f16 [NP][K] (transposed), bias -> bcomb[NP]
// hi/lo split: v = hi + lo with hi = f16(v), lo = f16(v - hi) -> ~22 mantissa bits
__global__ void k_pack(const float* __restrict__ Wb, const float* __restrict__ Wc,
                       const float* __restrict__ bc,
                       _Float16* __restrict__ WhT, _Float16* __restrict__ WlT,
                       float* __restrict__ bcomb, int K, int FB, int NP) {
    int idx = blockIdx.x * blockDim.x + threadIdx.x;
    if (idx < NP * K) {
        int n = idx / K, k = idx - n * K;
        float v = 0.f;
        if (n < FB) v = Wb[k * FB + n];
        else if (n < FB + 96) v = Wc[k * 96 + (n - FB)];
        _Float16 h = (_Float16)v;
        WhT[idx] = h;
        WlT[idx] = (_Float16)(v - (float)h);
    }
    if (idx < NP) bcomb[idx] = (idx >= FB && idx < FB + 96) ? bc[idx - FB] : 0.f;
}

// ---------------------------------------------------------------- f16-split MFMA GEMM
// C[M x LDC] = A[M x K](f32) @ W(pre-split f16 hi/lo, transposed [NP][K]) + bias
// 128x128 block, 4 waves as 2x2 of 64x64, mfma_f32_16x16x32_f16, BK=32.
// 3-term emulation: hh + h*l + l*h (al*bl dropped, ~2^-22 rel).
// LDS chunks XOR-swizzled by (row>>1)&3: fragment ds_read_b128 is 2-way (free)
// instead of 8-way. amdgpu_waves_per_eu(2,2): protect acc(64)+frags from the
// allocator's occupancy heuristic (R6/R7 evidence); MFMA kernels run fine at
// 8 waves/CU.
template<int K, int NP, int LDC>
__global__ __launch_bounds__(256) __attribute__((amdgpu_waves_per_eu(2, 2)))
void k_gemm_mfma(const float* __restrict__ A,
                 const _Float16* __restrict__ BhT,
                 const _Float16* __restrict__ BlT,
                 const float* __restrict__ bias,
                 float* __restrict__ C, int M) {
    __shared__ _Float16 Ah[128 * 32];
    __shared__ _Float16 Al[128 * 32];
    __shared__ _Float16 Bh[128 * 32];
    __shared__ _Float16 Bl[128 * 32];

    const int tid = threadIdx.x;
    const int m0 = blockIdx.y * 128, n0 = blockIdx.x * 128;
    const int lane = tid & 63, w = tid >> 6;
    const int wr = w >> 1, wc = w & 1;          // 2x2 wave grid, 64x64 each
    const int lr = lane & 15, lg = lane >> 4;   // fragment row / k-group

    // staging map: thread -> (row 0..127, k-half 0/1)
    const int srow = tid >> 1;
    const int shalf = tid & 1;
    const int ssw = (srow >> 1) & 3;
    const int sc0 = (shalf * 2 + 0) ^ ssw;
    const int sc1 = (shalf * 2 + 1) ^ ssw;

    f32x4 acc[4][4];
    #pragma unroll
    for (int i = 0; i < 4; i++)
        #pragma unroll
        for (int j = 0; j < 4; j++)
            acc[i][j] = (f32x4){0.f, 0.f, 0.f, 0.f};

    const int gm = m0 + srow;
    const bool avalid = gm < M;
    const float*     Ap  = A   + (size_t)(avalid ? gm : 0) * K + shalf * 16;
    const _Float16*  Bhp = BhT + (size_t)(n0 + srow) * K + shalf * 16;
    const _Float16*  Blp = BlT + (size_t)(n0 + srow) * K + shalf * 16;

    const float4 z4 = make_float4(0.f, 0.f, 0.f, 0.f);
    const int nT = K / 32;

    for (int t = 0; t < nT; t++) {
        // ---- issue global loads for this tile
        float4 fa[4];
        if (avalid) {
            const float* ap = Ap + t * 32;
            fa[0] = *(const float4*)(ap + 0);
            fa[1] = *(const float4*)(ap + 4);
            fa[2] = *(const float4*)(ap + 8);
            fa[3] = *(const float4*)(ap + 12);
        } else { fa[0] = z4; fa[1] = z4; fa[2] = z4; fa[3] = z4; }
        half8 sbh0 = *(const half8*)(Bhp + t * 32);
        half8 sbh1 = *(const half8*)(Bhp + t * 32 + 8);
        half8 sbl0 = *(const half8*)(Blp + t * 32);
        half8 sbl1 = *(const half8*)(Blp + t * 32 + 8);

        // ---- split A into hi/lo f16
        float av[16] = {fa[0].x, fa[0].y, fa[0].z, fa[0].w,
                        fa[1].x, fa[1].y, fa[1].z, fa[1].w,
                        fa[2].x, fa[2].y, fa[2].z, fa[2].w,
                        fa[3].x, fa[3].y, fa[3].z, fa[3].w};
        half8 h0, h1, l0, l1;
        #pragma unroll
        for (int v = 0; v < 8; v++) {
            _Float16 ha = (_Float16)av[v];
            h0[v] = ha; l0[v] = (_Float16)(av[v] - (float)ha);
            _Float16 hb = (_Float16)av[v + 8];
            h1[v] = hb; l1[v] = (_Float16)(av[v + 8] - (float)hb);
        }

        __syncthreads();   // all waves done reading previous tile
        *(half8*)&Ah[srow * 32 + sc0 * 8] = h0;
        *(half8*)&Ah[srow * 32 + sc1 * 8] = h1;
        *(half8*)&Al[srow * 32 + sc0 * 8] = l0;
        *(half8*)&Al[srow * 32 + sc1 * 8] = l1;
        *(half8*)&Bh[srow * 32 + sc0 * 8] = sbh0;
        *(half8*)&Bh[srow * 32 + sc1 * 8] = sbh1;
        *(half8*)&Bl[srow * 32 + sc0 * 8] = sbl0;
        *(half8*)&Bl[srow * 32 + sc1 * 8] = sbl1;
        __syncthreads();

        // ---- compute: 48 mfma (4m x 4n x 3 terms)
        half8 bhf[4], blf[4];
        #pragma unroll
        for (int j = 0; j < 4; j++) {
            int br = wc * 64 + j * 16 + lr;
            int bch = lg ^ ((br >> 1) & 3);
            bhf[j] = *(const half8*)&Bh[br * 32 + bch * 8];
            blf[j] = *(const half8*)&Bl[br * 32 + bch * 8];
        }
        #pragma unroll
        for (int i = 0; i < 4; i++) {
            int ar = wr * 64 + i * 16 + lr;
            int ach = lg ^ ((ar >> 1) & 3);
            half8 ahf = *(const half8*)&Ah[ar * 32 + ach * 8];
            half8 alf = *(const half8*)&Al[ar * 32 + ach * 8];
            #pragma unroll
            for (int j = 0; j < 4; j++) {
                acc[i][j] = __builtin_amdgcn_mfma_f32_16x16x32_f16(ahf, bhf[j], acc[i][j], 0, 0, 0);
                acc[i][j] = __builtin_amdgcn_mfma_f32_16x16x32_f16(alf, bhf[j], acc[i][j], 0, 0, 0);
                acc[i][j] = __builtin_amdgcn_mfma_f32_16x16x32_f16(ahf, blf[j], acc[i][j], 0, 0, 0);
            }
        }
    }

    // ---- epilogue: C row = (lane>>4)*4+reg (M side), col = lane&15 (N side)
    #pragma unroll
    for (int j = 0; j < 4; j++) {
        int col = n0 + wc * 64 + j * 16 + lr;
        if (col >= LDC) continue;
        float bv = bias[col];
        #pragma unroll
        for (int i = 0; i < 4; i++) {
            int rbase = m0 + wr * 64 + i * 16 + lg * 4;
            #pragma unroll
            for (int q = 0; q < 4; q++) {
                int r = rbase + q;
                if (r < M) C[(size_t)r * LDC + col] = acc[i][j][q] + bv;
            }
        }
    }
}

// ---------------------------------------------------------------- fused gather + 3 aggregators + combine (+relu / +log_softmax)
// one WAVE per node; lane owns a float2 feature pair; 4-edge manual unroll for MLP
template<int FB, int F, int DOUT, int FINAL, int LD>
__global__ __launch_bounds__(256) void k_agg(const float* __restrict__ fused,
                                             const float* __restrict__ bias,
                                             const int* __restrict__ rowptr,
                                             const int* __restrict__ csr_col,
                                             const float* __restrict__ csr_norm,
                                             float* __restrict__ out) {
    constexpr int NS  = (FB + 127) / 128;  // float2 slots per lane
    constexpr int OPL = (DOUT + 63) / 64;  // outputs per lane
    const int wid  = threadIdx.x >> 6;
    const int lane = threadIdx.x & 63;
    const int n = blockIdx.x * 4 + wid;    // grid is exactly NN/4 blocks

    __shared__ int   s_col[4][64];
    __shared__ float s_nrm[4][64];
    __shared__ float s_w[4][HEADS * KC];
    __shared__ float s_agg[4][KC * F];

    // stage combine weights (96 floats) for this node
    const float* wsrc = fused + (size_t)n * LD + FB;
    s_w[wid][lane] = wsrc[lane];
    if (lane < HEADS * KC - 64) s_w[wid][64 + lane] = wsrc[64 + lane];

    const int start = rowptr[n], end = rowptr[n + 1];
    float2 sum[NS], ssum[NS], mx[NS];
    #pragma unroll
    for (int s = 0; s < NS; s++) {
        sum[s] = make_float2(0.f, 0.f);
        ssum[s] = make_float2(0.f, 0.f);
        mx[s] = make_float2(-3.402823466e38f, -3.402823466e38f);
    }

    for (int e0 = start; e0 < end; e0 += 64) {
        int cnt = min(64, end - e0);
        if (lane < cnt) {
            s_col[wid][lane] = csr_col[e0 + lane];
            s_nrm[wid][lane] = csr_norm[e0 + lane];
        }
        __builtin_amdgcn_wave_barrier();   // wave-synchronous: in-order LDS pipe makes RAW safe
        int j = 0;
        for (; j + 4 <= cnt; j += 4) {
            const int4   cc = *(const int4*)&s_col[wid][j];
            const float4 nn = *(const float4*)&s_nrm[wid][j];
            #pragma unroll
            for (int s = 0; s < NS; s++) {
                const int feat = s * 128 + lane * 2;
                if (feat < FB) {
                    const float2 v0 = *(const float2*)&fused[(size_t)cc.x * LD + feat];
                    const float2 v1 = *(const float2*)&fused[(size_t)cc.y * LD + feat];
                    const float2 v2 = *(const float2*)&fused[(size_t)cc.z * LD + feat];
                    const float2 v3 = *(const float2*)&fused[(size_t)cc.w * LD + feat];
                    sum[s].x += (v0.x + v1.x) + (v2.x + v3.x);
                    sum[s].y += (v0.y + v1.y) + (v2.y + v3.y);
                    ssum[s].x = fmaf(v0.x, nn.x, fmaf(v1.x, nn.y, fmaf(v2.x, nn.z, fmaf(v3.x, nn.w, ssum[s].x))));
                    ssum[s].y = fmaf(v0.y, nn.x, fmaf(v1.y, nn.y, fmaf(v2.y, nn.z, fmaf(v3.y, nn.w, ssum[s].y))));
                    mx[s].x = fmaxf(mx[s].x, fmaxf(fmaxf(v0.x, v1.x), fmaxf(v2.x, v3.x)));
                    mx[s].y = fmaxf(mx[s].y, fmaxf(fmaxf(v0.y, v1.y), fmaxf(v2.y, v3.y)));
                }
            }
        }
        for (; j < cnt; j++) {
            const int   c  = s_col[wid][j];
            const float nr = s_nrm[wid][j];
            #pragma unroll
            for (int s = 0; s < NS; s++) {
                const int feat = s * 128 + lane * 2;
                if (feat < FB) {
                    const float2 v = *(const float2*)&fused[(size_t)c * LD + feat];
                    sum[s].x += v.x;             sum[s].y += v.y;
                    ssum[s].x = fmaf(v.x, nr, ssum[s].x);
                    ssum[s].y = fmaf(v.y, nr, ssum[s].y);
                    mx[s].x = fmaxf(mx[s].x, v.x);
                    mx[s].y = fmaxf(mx[s].y, v.y);
                }
            }
        }
        __builtin_amdgcn_wave_barrier();
    }

    const float degf = (float)(end - start);
    const float rdeg = 1.f / fmaxf(degf, 1.f);
    const bool nonempty = degf > 0.f;
    #pragma unroll
    for (int s = 0; s < NS; s++) {
        const int feat = s * 128 + lane * 2;
        if (feat < FB) {
            const int nb = feat / F, f = feat - nb * F;
            float2 mean = make_float2(sum[s].x * rdeg, sum[s].y * rdeg);
            float2 mxv  = nonempty ? mx[s] : make_float2(0.f, 0.f);
            *(float2*)&s_agg[wid][(0 * NB + nb) * F + f] = ssum[s];
            *(float2*)&s_agg[wid][(1 * NB + nb) * F + f] = mean;
            *(float2*)&s_agg[wid][(2 * NB + nb) * F + f] = mxv;
        }
    }
    __builtin_amdgcn_wave_barrier();

    float ov[OPL];
    #pragma unroll
    for (int q = 0; q < OPL; q++) {
        int o = lane + q * 64;
        if (o < DOUT) {
            int h = o / F, f = o - h * F;
            float v = bias[o];
            #pragma unroll
            for (int k = 0; k < KC; k++) v = fmaf(s_w[wid][h * KC + k], s_agg[wid][k * F + f], v);
            ov[q] = v;
        } else {
            ov[q] = -3.402823466e38f;
        }
    }

    if constexpr (FINAL == 0) {
        #pragma unroll
        for (int q = 0; q < OPL; q++) {
            int o = lane + q * 64;
            if (o < DOUT) out[(size_t)n * DOUT + o] = fmaxf(ov[q], 0.f);
        }
    } else {
        float m = -3.402823466e38f;
        #pragma unroll
        for (int q = 0; q < OPL; q++) { int o = lane + q * 64; if (o < OUT_T) m = fmaxf(m, ov[q]); }
        #pragma unroll
        for (int off = 32; off >= 1; off >>= 1) m = fmaxf(m, __shfl_xor(m, off, 64));
        float s = 0.f;
        #pragma unroll
        for (int q = 0; q < OPL; q++) { int o = lane + q * 64; if (o < OUT_T) s += expf(ov[q] - m); }
        #pragma unroll
        for (int off = 32; off >= 1; off >>= 1) s += __shfl_xor(s, off, 64);
        float lse = m + logf(s);
        #pragma unroll
        for (int q = 0; q < OPL; q++) {
            int o = lane + q * 64;
            if (o < OUT_T) out[(size_t)n * OUT_T + o] = ov[q] - lse;
        }
    }
}

// ---------------------------------------------------------------- launch
extern "C" void kernel_launch(void* const* d_in, const int* in_sizes, int n_in,
                              void* d_out, int out_size, void* d_ws, size_t ws_size,
                              hipStream_t stream) {
    const float* x   = (const float*)d_in[0];
    const int*   ei  = (const int*)d_in[1];
    const int*   row = ei;
    const int*   col = ei + NE;
    const float* Wb0 = (const float*)d_in[2];
    const float* Wc0 = (const float*)d_in[3];
    const float* bc0 = (const float*)d_in[4];
    const float* b0  = (const float*)d_in[5];
    const float* Wb1 = (const float*)d_in[6];
    const float* Wc1 = (const float*)d_in[7];
    const float* bc1 = (const float*)d_in[8];
    const float* b1  = (const float*)d_in[9];
    const float* Wb2 = (const float*)d_in[10];
    const float* Wc2 = (const float*)d_in[11];
    const float* bc2 = (const float*)d_in[12];
    const float* b2  = (const float*)d_in[13];
    float* out = (float*)d_out;

    // workspace carve (256B aligned slots, elems are f32-sized)
    char* w = (char*)d_ws;
    size_t off = 0;
    auto carve = [&](size_t elems) { void* p = w + off; off += ((elems * 4 + 255) / 256) * 256; return p; };
    int*   deg      = (int*)  carve(NN);
    int*   cursor   = (int*)  carve(NN);
    int*   rowptr   = (int*)  carve(NN + 1);
    float* dinv     = (float*)carve(NN);
    int*   csr_col  = (int*)  carve(NE);
    float* csr_norm = (float*)carve(NE);
    float* fused    = (float*)carve((size_t)NN * 272);   // GEMM out (bases|comb), reused all 3 layers
    float* h2       = (float*)carve((size_t)NN * 256);
    _Float16* WhT   = (_Float16*)carve(49152);           // 384*256 f16 = 192KB
    _Float16* WlT   = (_Float16*)carve(49152);
    float* bcomb    = (float*)carve(384);
    float* h1       = out;   // layer-0 hidden in d_out slack (51.2MB < 69.8MB)

    hipMemsetAsync(deg, 0, NN * sizeof(int), stream);
    hipMemsetAsync(cursor, 0, NN * sizeof(int), stream);

    k_count<<<(NE + 255) / 256, 256, 0, stream>>>(row, deg);
    k_scan<<<1, 1024, 0, stream>>>(deg, rowptr);
    k_dinv<<<(NN + 255) / 256, 256, 0, stream>>>(deg, dinv);
    k_fill<<<(NE + 255) / 256, 256, 0, stream>>>(row, col, rowptr, cursor, dinv, csr_col, csr_norm);

    const int gy = (NN + 127) / 128;   // 391

    // ---- layer 0: K=128, N=224 (FB=128 | 96), NP=256
    k_pack<<<(256 * 128 + 255) / 256, 256, 0, stream>>>(Wb0, Wc0, bc0, WhT, WlT, bcomb, 128, 128, 256);
    k_gemm_mfma<128, 256, 224><<<dim3(2, gy), 256, 0, stream>>>(x, WhT, WlT, bcomb, fused, NN);
    k_agg<128, 32, 256, 0, 224><<<NN / 4, 256, 0, stream>>>(fused, b0, rowptr, csr_col, csr_norm, h1);

    // ---- layer 1: K=256, N=224, NP=256
    k_pack<<<(256 * 256 + 255) / 256, 256, 0, stream>>>(Wb1, Wc1, bc1, WhT, WlT, bcomb, 256, 128, 256);
    k_gemm_mfma<256, 256, 224><<<dim3(2, gy), 256, 0, stream>>>(h1, WhT, WlT, bcomb, fused, NN);
    k_agg<128, 32, 256, 0, 224><<<NN / 4, 256, 0, stream>>>(fused, b1, rowptr, csr_col, csr_norm, h2);

    // ---- layer 2: K=256, N=272 (FB=176 | 96), NP=384, fused log_softmax -> d_out
    k_pack<<<(384 * 256 + 255) / 256, 256, 0, stream>>>(Wb2, Wc2, bc2, WhT, WlT, bcomb, 256, 176, 384);
    k_gemm_mfma<256, 384, 272><<<dim3(3, gy), 256, 0, stream>>>(h2, WhT, WlT, bcomb, fused, NN);
    k_agg<176, 44, 352, 1, 272><<<NN / 4, 256, 0, stream>>>(fused, b2, rowptr, csr_col, csr_norm, out);
}